// Round 9
// baseline (628.771 us; speedup 1.0000x reference)
//
#include <hip/hip_runtime.h>
#include <hip/hip_cooperative_groups.h>
#include <hip/hip_bf16.h>
#include <math.h>
#include <stdint.h>

namespace cg = cooperative_groups;

// ---------------------------------------------------------------------------
// DeepSetLayer / graph-attention — SINGLE cooperative kernel, phases split by
// grid.sync(): zero | qk-MFMA + histogram(+u16 rank) + Wc-convert | scan |
// scan-add | scatter (atomic-free) | attn (wave/node) | final (bf16 MFMA).
// u16 edge ids require N <= 65535 (problem: N=50000).
// ---------------------------------------------------------------------------

#define IN_F 128
#define SMALL 12
#define QK_PAD 16
#define SCAN_ITEMS 8
#define SCAN_CHUNK 2048  // 256 threads * 8 items

typedef __attribute__((ext_vector_type(8))) short short8;   // 8 x bf16
typedef __attribute__((ext_vector_type(4))) float f32x4;

__device__ __forceinline__ unsigned short f2bf(float f) {
    union { float f; unsigned u; } v; v.f = f;
    unsigned r = v.u + 0x7fff + ((v.u >> 16) & 1);  // RNE
    return (unsigned short)(r >> 16);
}

__device__ __forceinline__ float2 bf2x2(unsigned v) {
    union { unsigned u; float f; } a, b;
    a.u = v << 16;
    b.u = v & 0xffff0000u;
    return make_float2(a.f, b.f);
}

__device__ __forceinline__ float dot12(const float* __restrict__ qrow,
                                       float4 c0, float4 c1, float4 c2) {
    float4 a = ((const float4*)qrow)[0];
    float4 b = ((const float4*)qrow)[1];
    float4 c = ((const float4*)qrow)[2];
    return a.x*c0.x + a.y*c0.y + a.z*c0.z + a.w*c0.w
         + b.x*c1.x + b.y*c1.y + b.z*c1.z + b.w*c1.w
         + c.x*c2.x + c.y*c2.y + c.z*c2.z + c.w*c2.w;
}

__device__ __forceinline__ short8 ld_bf8(const float* p) {
    float4 x0 = *(const float4*)p;
    float4 x1 = *(const float4*)(p + 4);
    short8 a;
    a[0] = (short)f2bf(x0.x); a[1] = (short)f2bf(x0.y);
    a[2] = (short)f2bf(x0.z); a[3] = (short)f2bf(x0.w);
    a[4] = (short)f2bf(x1.x); a[5] = (short)f2bf(x1.y);
    a[6] = (short)f2bf(x1.z); a[7] = (short)f2bf(x1.w);
    return a;
}

__global__ __launch_bounds__(256, 4) void mega_kernel(
    const float* __restrict__ nd, const int* __restrict__ src,
    const int* __restrict__ dst,
    const float* __restrict__ Wq, const float* __restrict__ bq,
    const float* __restrict__ Wk, const float* __restrict__ bk,
    const float* __restrict__ W1, const float* __restrict__ W2,
    const float* __restrict__ b2,
    float* __restrict__ q, float* __restrict__ kf,
    unsigned short* __restrict__ ndb, unsigned short* __restrict__ Wc,
    int* __restrict__ off, int* __restrict__ bsum,
    unsigned short* __restrict__ rank, unsigned short* __restrict__ esrc,
    float* __restrict__ out, int N, int E)
{
    cg::grid_group grid = cg::this_grid();
    __shared__ int tsum[256];
    __shared__ int pre2[2];

    int t = threadIdx.x;
    int b = blockIdx.x;
    int NBLK = gridDim.x;
    int gsz = NBLK * 256;
    int gid = b * 256 + t;
    int ET = E + N;
    int wv = t >> 6;
    int lane = t & 63;
    int col = lane & 15;
    int quad = lane >> 4;
    int NT = (N + 63) >> 6;  // 64-node tiles

    // ---- phase 0: zero counts off[0..N] ------------------------------------
    for (int i = gid; i <= N; i += gsz) off[i] = 0;
    grid.sync();

    // ---- phase 1a: q|k projection via MFMA (16 nodes/wave) + ndb convert ---
    for (int tb = b; tb < NT; tb += NBLK) {
        int tbase = tb * 64 + wv * 16;
        int arow = tbase + col;
        int rowc = (arow < N) ? arow : (N - 1);
        const float* ap = nd + (size_t)rowc * IN_F + quad * 8;
        unsigned short* np = ndb + (size_t)arow * IN_F + quad * 8;

        // B tile0 cols: [Wq rows 0..11 | Wk rows 0..3]; tile1: [Wk 4..11 | 0]
        const float* w0 = ((col < 12) ? (Wq + (size_t)col * IN_F)
                                      : (Wk + (size_t)(col - 12) * IN_F)) + quad * 8;
        const float* w1 = Wk + (size_t)((col < 8) ? (col + 4) : 4) * IN_F + quad * 8;
        bool hasw1 = (col < 8);

        f32x4 acc0 = (f32x4)0.f, acc1 = (f32x4)0.f;
#pragma unroll
        for (int ks = 0; ks < 4; ks++) {
            int k0 = ks * 32;
            short8 a = ld_bf8(ap + k0);
            if (arow < N) *(short8*)(np + k0) = a;
            short8 bb0 = ld_bf8(w0 + k0);
            short8 bb1 = hasw1 ? ld_bf8(w1 + k0) : (short8)0;
            acc0 = __builtin_amdgcn_mfma_f32_16x16x32_bf16(a, bb0, acc0, 0, 0, 0);
            acc1 = __builtin_amdgcn_mfma_f32_16x16x32_bf16(a, bb1, acc1, 0, 0, 0);
        }
        float bias0 = (col < 12) ? bq[col] : bk[col - 12];
        float bias1 = (col < 8) ? bk[col + 4] : 0.f;
#pragma unroll
        for (int r = 0; r < 4; r++) {
            int node = tbase + quad * 4 + r;
            if (node < N) {
                float v0 = acc0[r] + bias0;
                if (col < 12) q[(size_t)node * QK_PAD + col] = tanhf(v0);
                else          kf[(size_t)node * QK_PAD + (col - 12)] = v0;
                if (hasw1)    kf[(size_t)node * QK_PAD + col + 4] = acc1[r] + bias1;
            }
        }
    }
    // ---- phase 1b: dst histogram + u16 rank --------------------------------
    for (int i = gid; i < ET; i += gsz) {
        int d = (i < E) ? dst[i] : (i - E);
        rank[i] = (unsigned short)atomicAdd(&off[d], 1);
    }
    // ---- phase 1c: convert [W1|W2] -> bf16 Wc[128][256] --------------------
    for (int i = gid; i < 128 * 256; i += gsz) {
        int f = i >> 8, k = i & 255;
        float v = (k < 128) ? W1[f * 128 + k] : W2[f * 128 + (k - 128)];
        Wc[i] = f2bf(v);
    }
    grid.sync();

    // ---- phase 2a: per-block local exclusive scan + block sums -------------
    int NBS = (N + SCAN_CHUNK - 1) / SCAN_CHUNK;  // 25
    if (b < NBS) {
        int base = b * SCAN_CHUNK + t * SCAN_ITEMS;
        int v[SCAN_ITEMS];
        int s = 0;
#pragma unroll
        for (int i = 0; i < SCAN_ITEMS; i++) {
            int idx = base + i;
            v[i] = (idx < N) ? off[idx] : 0;
            s += v[i];
        }
        tsum[t] = s;
        __syncthreads();
        for (int d = 1; d < 256; d <<= 1) {
            int x = (t >= d) ? tsum[t - d] : 0;
            __syncthreads();
            tsum[t] += x;
            __syncthreads();
        }
        int excl = (t == 0) ? 0 : tsum[t - 1];
#pragma unroll
        for (int i = 0; i < SCAN_ITEMS; i++) {
            int idx = base + i;
            if (idx < N) off[idx] = excl;
            excl += v[i];
        }
        if (t == 255) bsum[b] = tsum[255];
    }
    grid.sync();

    // ---- phase 2b: add block prefixes, set off[N] --------------------------
    if (b < NBS) {
        if (t == 0) {
            int p = 0, tot = 0;
            for (int i = 0; i < NBS; i++) {
                int v = bsum[i];
                if (i < b) p += v;
                tot += v;
            }
            pre2[0] = p; pre2[1] = tot;
        }
        __syncthreads();
        int add = pre2[0];
        if (b == 0 && t == 0) off[N] = pre2[1];
        int base = b * SCAN_CHUNK + t * SCAN_ITEMS;
#pragma unroll
        for (int i = 0; i < SCAN_ITEMS; i++) {
            int j = base + i;
            if (j < N) off[j] += add;
        }
    }
    grid.sync();

    // ---- phase 3: scatter edge src ids (atomic-free) -----------------------
    for (int i = gid; i < ET; i += gsz) {
        int d, s;
        if (i < E) { d = dst[i]; s = src[i]; }
        else       { d = i - E; s = d; }
        esrc[off[d] + (int)rank[i]] = (unsigned short)s;
    }
    grid.sync();

    // ---- phase 4: per-dst softmax + weighted bf16 gather (wave per node) ---
    {
        const float INVDK = 0.28867513459481287f;  // 1/sqrt(12)
        float* att = out;
        for (int wid = b * 4 + wv; wid < N; wid += NBLK * 4) {
            int start = off[wid];
            int deg = off[wid + 1] - start;

            const float4* kp = (const float4*)(kf + (size_t)wid * QK_PAD);
            float4 c0 = kp[0], c1 = kp[1], c2 = kp[2];

            float2 acc = make_float2(0.f, 0.f);
            float inv;

            if (deg <= 64) {
                float sc = -INFINITY;
                int si = 0;
                if (lane < deg) {
                    si = (int)esrc[start + lane];
                    sc = dot12(q + (size_t)si * QK_PAD, c0, c1, c2) * INVDK;
                }
                float m = sc;
#pragma unroll
                for (int o = 32; o > 0; o >>= 1) m = fmaxf(m, __shfl_xor(m, o));
                float w = (lane < deg) ? __expf(sc - m) : 0.f;
                float lsum = w;
#pragma unroll
                for (int o = 32; o > 0; o >>= 1) lsum += __shfl_xor(lsum, o);
                inv = 1.f / lsum;

                int i = 0;
                for (; i + 4 <= deg; i += 4) {
                    float w0 = __shfl(w, i);     int r0 = __shfl(si, i);
                    float w1 = __shfl(w, i + 1); int r1 = __shfl(si, i + 1);
                    float w2 = __shfl(w, i + 2); int r2 = __shfl(si, i + 2);
                    float w3 = __shfl(w, i + 3); int r3 = __shfl(si, i + 3);
                    unsigned v0 = *(const unsigned*)(ndb + (size_t)r0 * IN_F + lane * 2);
                    unsigned v1 = *(const unsigned*)(ndb + (size_t)r1 * IN_F + lane * 2);
                    unsigned v2 = *(const unsigned*)(ndb + (size_t)r2 * IN_F + lane * 2);
                    unsigned v3 = *(const unsigned*)(ndb + (size_t)r3 * IN_F + lane * 2);
                    float2 f0 = bf2x2(v0), f1 = bf2x2(v1), f2 = bf2x2(v2), f3 = bf2x2(v3);
                    acc.x += w0 * f0.x + w1 * f1.x + w2 * f2.x + w3 * f3.x;
                    acc.y += w0 * f0.y + w1 * f1.y + w2 * f2.y + w3 * f3.y;
                }
                for (; i < deg; i++) {
                    float wi = __shfl(w, i);
                    int r = __shfl(si, i);
                    float2 f = bf2x2(*(const unsigned*)(ndb + (size_t)r * IN_F + lane * 2));
                    acc.x += wi * f.x;
                    acc.y += wi * f.y;
                }
            } else {
                // generic (deg > 64): recompute scores per pass
                float m = -INFINITY;
                for (int i = lane; i < deg; i += 64) {
                    int s2 = (int)esrc[start + i];
                    m = fmaxf(m, dot12(q + (size_t)s2 * QK_PAD, c0, c1, c2) * INVDK);
                }
#pragma unroll
                for (int o = 32; o > 0; o >>= 1) m = fmaxf(m, __shfl_xor(m, o));
                float lsum = 0.f;
                for (int i = lane; i < deg; i += 64) {
                    int s2 = (int)esrc[start + i];
                    lsum += __expf(dot12(q + (size_t)s2 * QK_PAD, c0, c1, c2) * INVDK - m);
                }
#pragma unroll
                for (int o = 32; o > 0; o >>= 1) lsum += __shfl_xor(lsum, o);
                inv = 1.f / lsum;
                for (int base2 = 0; base2 < deg; base2 += 64) {
                    int cnt2 = deg - base2; if (cnt2 > 64) cnt2 = 64;
                    float w = 0.f; int si = 0;
                    if (lane < cnt2) {
                        si = (int)esrc[start + base2 + lane];
                        w = __expf(dot12(q + (size_t)si * QK_PAD, c0, c1, c2) * INVDK - m);
                    }
                    for (int i = 0; i < cnt2; i++) {
                        float wi = __shfl(w, i);
                        int r = __shfl(si, i);
                        float2 f = bf2x2(*(const unsigned*)(ndb + (size_t)r * IN_F + lane * 2));
                        acc.x += wi * f.x;
                        acc.y += wi * f.y;
                    }
                }
            }
            acc.x *= inv; acc.y *= inv;
            ((float2*)(att + (size_t)wid * IN_F))[lane] = acc;
        }
    }
    grid.sync();

    // ---- phase 5: out = relu(rownorm(nd@W1^T + att@W2^T + b2)), bf16 MFMA --
    {
        const float* att = out;  // aliases out; tile-local read-before-write
        for (int tb = b; tb < NT; tb += NBLK) {
            int nbase = tb * 64;
            int arow = nbase + wv * 16 + col;
            int rowc = (arow < N) ? arow : (N - 1);
            const unsigned short* a0p = ndb + (size_t)rowc * IN_F + quad * 8;
            const float* a1p = ((arow < N) ? att : nd) + (size_t)rowc * IN_F + quad * 8;

            f32x4 acc[8];
#pragma unroll
            for (int i = 0; i < 8; i++) acc[i] = (f32x4)0.f;

#pragma unroll
            for (int ks = 0; ks < 8; ks++) {
                int k0 = ks * 32;
                short8 a;
                if (ks < 4) a = *(const short8*)(a0p + k0);
                else        a = ld_bf8(a1p + (k0 - 128));
#pragma unroll
                for (int ft = 0; ft < 8; ft++) {
                    int n = ft * 16 + col;
                    short8 bb = *(const short8*)(Wc + (size_t)n * 256 + k0 + quad * 8);
                    acc[ft] = __builtin_amdgcn_mfma_f32_16x16x32_bf16(a, bb, acc[ft], 0, 0, 0);
                }
            }

            float bias[8];
#pragma unroll
            for (int ft = 0; ft < 8; ft++) bias[ft] = b2[ft * 16 + col];

#pragma unroll
            for (int r = 0; r < 4; r++) {
                int node = nbase + wv * 16 + quad * 4 + r;
                float v[8];
                float ps = 0.f;
#pragma unroll
                for (int ft = 0; ft < 8; ft++) {
                    v[ft] = acc[ft][r] + bias[ft];
                    ps += v[ft] * v[ft];
                }
                ps += __shfl_xor(ps, 1);
                ps += __shfl_xor(ps, 2);
                ps += __shfl_xor(ps, 4);
                ps += __shfl_xor(ps, 8);
                float rn = rsqrtf(ps);
                if (node < N) {
                    float* op = out + (size_t)node * 128 + col;
#pragma unroll
                    for (int ft = 0; ft < 8; ft++)
                        op[ft * 16] = fmaxf(v[ft] * rn, 0.f);
                }
            }
        }
    }
}

// ---------------------------------------------------------------------------
static inline char* align_up(char* p, size_t a) {
    return (char*)(((uintptr_t)p + (a - 1)) & ~(uintptr_t)(a - 1));
}

extern "C" void kernel_launch(void* const* d_in, const int* in_sizes, int n_in,
                              void* d_out, int out_size, void* d_ws, size_t ws_size,
                              hipStream_t stream) {
    const float* node_data = (const float*)d_in[0];
    const int*   src       = (const int*)d_in[1];
    const int*   dst       = (const int*)d_in[2];
    const float* Wq        = (const float*)d_in[3];
    const float* bq        = (const float*)d_in[4];
    const float* Wk        = (const float*)d_in[5];
    const float* bk        = (const float*)d_in[6];
    const float* W1        = (const float*)d_in[7];
    const float* W2        = (const float*)d_in[8];
    const float* b2        = (const float*)d_in[9];
    float* out = (float*)d_out;

    int N = in_sizes[0] / IN_F;
    int E = in_sizes[1];
    int ET = E + N;

    char* w = (char*)d_ws;
    float* q  = (float*)w;  w += (size_t)N * QK_PAD * sizeof(float);
    float* kf = (float*)w;  w += (size_t)N * QK_PAD * sizeof(float);
    w = align_up(w, 256);
    unsigned short* ndb = (unsigned short*)w;  w += (size_t)N * IN_F * sizeof(unsigned short);
    w = align_up(w, 256);
    unsigned short* Wc = (unsigned short*)w;  w += 128 * 256 * sizeof(unsigned short);
    int* off  = (int*)w;  w += (size_t)(N + 1) * sizeof(int);
    int* bsum = (int*)w;  w += 1024 * sizeof(int);
    unsigned short* rank = (unsigned short*)w;  w += (size_t)ET * sizeof(unsigned short);
    w = align_up(w, 256);
    unsigned short* esrc = (unsigned short*)w;  w += (size_t)ET * sizeof(unsigned short);

    // cooperative grid: all blocks resident. MI355X = 256 CUs.
    int occ = 0;
    hipOccupancyMaxActiveBlocksPerMultiprocessor(&occ, mega_kernel, 256, 0);
    if (occ < 1) occ = 1;
    long long grid_ll = (long long)occ * 256;
    int grid = (grid_ll > 1024) ? 1024 : (int)grid_ll;

    void* args[] = {
        (void*)&node_data, (void*)&src, (void*)&dst,
        (void*)&Wq, (void*)&bq, (void*)&Wk, (void*)&bk,
        (void*)&W1, (void*)&W2, (void*)&b2,
        (void*)&q, (void*)&kf, (void*)&ndb, (void*)&Wc,
        (void*)&off, (void*)&bsum, (void*)&rank, (void*)&esrc,
        (void*)&out, (void*)&N, (void*)&E
    };
    hipLaunchCooperativeKernel((const void*)mega_kernel, dim3(grid), dim3(256),
                               args, 0, stream);
}

// Round 10
// 231.757 us; speedup vs baseline: 2.7131x; 2.7131x over previous
//
#include <hip/hip_runtime.h>
#include <hip/hip_bf16.h>
#include <math.h>
#include <stdint.h>

// ---------------------------------------------------------------------------
// DeepSetLayer / graph-attention fused pipeline.
// Inputs: node_data[N,128] f32, src[E] i32, dst[E] i32, Wq[12,128], bq[12],
//         Wk[12,128], bk[12], W1[128,128], W2[128,128], b2[128]
// Self-loops appended: total edges ET = E + N.
// prep: MFMA q/k projection + nd->bf16, histogram(+u16 rank), Wc convert.
// CSR: scan + atomic-free scatter (u16 ids; requires N <= 65535).
// attn_final: block owns 64 nodes; attn (wave/node, bf16 gather) -> att rows
//   in LDS (bf16) -> barrier -> bf16 MFMA GEMM + bias + row-L2-norm + relu.
// ---------------------------------------------------------------------------

#define IN_F 128
#define SMALL 12
#define QK_PAD 16
#define SCAN_ITEMS 8
#define SCAN_CHUNK 2048  // 256 threads * 8 items
#define ALD 136          // att_lds row stride (ushorts); 68 words = 4 mod 32

typedef __attribute__((ext_vector_type(8))) short short8;   // 8 x bf16
typedef __attribute__((ext_vector_type(4))) float f32x4;

__device__ __forceinline__ unsigned short f2bf(float f) {
    union { float f; unsigned u; } v; v.f = f;
    unsigned r = v.u + 0x7fff + ((v.u >> 16) & 1);  // RNE
    return (unsigned short)(r >> 16);
}

__device__ __forceinline__ float2 bf2x2(unsigned v) {
    union { unsigned u; float f; } a, b;
    a.u = v << 16;
    b.u = v & 0xffff0000u;
    return make_float2(a.f, b.f);
}

__device__ __forceinline__ float dot12(const float* __restrict__ qrow,
                                       float4 c0, float4 c1, float4 c2) {
    float4 a = ((const float4*)qrow)[0];
    float4 b = ((const float4*)qrow)[1];
    float4 c = ((const float4*)qrow)[2];
    return a.x*c0.x + a.y*c0.y + a.z*c0.z + a.w*c0.w
         + b.x*c1.x + b.y*c1.y + b.z*c1.z + b.w*c1.w
         + c.x*c2.x + c.y*c2.y + c.z*c2.z + c.w*c2.w;
}

__device__ __forceinline__ short8 ld_bf8(const float* p) {
    float4 x0 = *(const float4*)p;
    float4 x1 = *(const float4*)(p + 4);
    short8 a;
    a[0] = (short)f2bf(x0.x); a[1] = (short)f2bf(x0.y);
    a[2] = (short)f2bf(x0.z); a[3] = (short)f2bf(x0.w);
    a[4] = (short)f2bf(x1.x); a[5] = (short)f2bf(x1.y);
    a[6] = (short)f2bf(x1.z); a[7] = (short)f2bf(x1.w);
    return a;
}

// ---- prep kernel (256 thr) -------------------------------------------------
// blocks [0, NBQK):       MFMA q/k projection + ndb convert (16 nodes/wave)
// blocks [NBQK, +NBCNT):  dst histogram + u16 rank (grid-stride)
// blocks [rest):          convert [W1|W2] -> bf16 Wc[128][256]
__global__ __launch_bounds__(256) void prep_kernel(
    const float* __restrict__ nd,
    const float* __restrict__ Wq, const float* __restrict__ bq,
    const float* __restrict__ Wk, const float* __restrict__ bk,
    const int* __restrict__ dst,
    const float* __restrict__ W1, const float* __restrict__ W2,
    float* __restrict__ q, float* __restrict__ kf,
    unsigned short* __restrict__ ndb, int* __restrict__ cnt,
    unsigned short* __restrict__ rank, unsigned short* __restrict__ Wc,
    int N, int E, int NBQK, int NBCNT)
{
    int t = threadIdx.x;
    int b = blockIdx.x;

    if (b < NBQK) {
        int wv = t >> 6;
        int lane = t & 63;
        int col = lane & 15;
        int quad = lane >> 4;
        int tbase = b * 64 + wv * 16;

        int arow = tbase + col;
        int rowc = (arow < N) ? arow : (N - 1);
        const float* ap = nd + (size_t)rowc * IN_F + quad * 8;
        unsigned short* np = ndb + (size_t)arow * IN_F + quad * 8;

        // B tile0 cols: [Wq rows 0..11 | Wk rows 0..3]; tile1: [Wk 4..11 | 0]
        const float* w0 = ((col < 12) ? (Wq + (size_t)col * IN_F)
                                      : (Wk + (size_t)(col - 12) * IN_F)) + quad * 8;
        const float* w1 = Wk + (size_t)((col < 8) ? (col + 4) : 4) * IN_F + quad * 8;
        bool hasw1 = (col < 8);

        f32x4 acc0 = (f32x4)0.f, acc1 = (f32x4)0.f;
#pragma unroll
        for (int ks = 0; ks < 4; ks++) {
            int k0 = ks * 32;
            short8 a = ld_bf8(ap + k0);
            if (arow < N) *(short8*)(np + k0) = a;
            short8 bb0 = ld_bf8(w0 + k0);
            short8 bb1 = hasw1 ? ld_bf8(w1 + k0) : (short8)0;
            acc0 = __builtin_amdgcn_mfma_f32_16x16x32_bf16(a, bb0, acc0, 0, 0, 0);
            acc1 = __builtin_amdgcn_mfma_f32_16x16x32_bf16(a, bb1, acc1, 0, 0, 0);
        }
        float bias0 = (col < 12) ? bq[col] : bk[col - 12];
        float bias1 = (col < 8) ? bk[col + 4] : 0.f;
#pragma unroll
        for (int r = 0; r < 4; r++) {
            int node = tbase + quad * 4 + r;
            if (node < N) {
                float v0 = acc0[r] + bias0;
                if (col < 12) q[(size_t)node * QK_PAD + col] = tanhf(v0);
                else          kf[(size_t)node * QK_PAD + (col - 12)] = v0;
                if (hasw1)    kf[(size_t)node * QK_PAD + col + 4] = acc1[r] + bias1;
            }
        }
    } else if (b < NBQK + NBCNT) {
        int ET = E + N;
        int stride = NBCNT * 256;
        for (int i = (b - NBQK) * 256 + t; i < ET; i += stride) {
            int d = (i < E) ? dst[i] : (i - E);
            rank[i] = (unsigned short)atomicAdd(&cnt[d], 1);
        }
    } else {
        int idx = (b - NBQK - NBCNT) * 256 + t;  // 0..32767
        int f = idx >> 8, k = idx & 255;
        float v = (k < 128) ? W1[f * 128 + k] : W2[f * 128 + (k - 128)];
        Wc[idx] = f2bf(v);
    }
}

// ---- scan phase 1: per-block local exclusive scan (in-place) + block sums --
__global__ __launch_bounds__(256) void scan_local_kernel(
    int* __restrict__ off, int* __restrict__ bsum, int N)
{
    __shared__ int tsum[256];
    int t = threadIdx.x;
    int base = blockIdx.x * SCAN_CHUNK + t * SCAN_ITEMS;
    int v[SCAN_ITEMS];
    int s = 0;
#pragma unroll
    for (int i = 0; i < SCAN_ITEMS; i++) {
        int idx = base + i;
        v[i] = (idx < N) ? off[idx] : 0;
        s += v[i];
    }
    tsum[t] = s;
    __syncthreads();
    for (int d = 1; d < 256; d <<= 1) {
        int x = (t >= d) ? tsum[t - d] : 0;
        __syncthreads();
        tsum[t] += x;
        __syncthreads();
    }
    int excl = (t == 0) ? 0 : tsum[t - 1];
#pragma unroll
    for (int i = 0; i < SCAN_ITEMS; i++) {
        int idx = base + i;
        if (idx < N) off[idx] = excl;
        excl += v[i];
    }
    if (t == 255) bsum[blockIdx.x] = tsum[255];
}

// ---- scan phase 2: add block offsets (bsum scanned inline) -----------------
__global__ __launch_bounds__(256) void scan_add_kernel(
    int* __restrict__ off, const int* __restrict__ bsum, int N, int NB)
{
    __shared__ int pre2[2];
    int t = threadIdx.x;
    if (t == 0) {
        int p = 0, tot = 0;
        for (int i = 0; i < NB; i++) {
            int v = bsum[i];
            if (i < (int)blockIdx.x) p += v;
            tot += v;
        }
        pre2[0] = p; pre2[1] = tot;
    }
    __syncthreads();
    int add = pre2[0];
    if (blockIdx.x == 0 && t == 0) off[N] = pre2[1];  // grand total = E + N

    int base = blockIdx.x * SCAN_CHUNK + t * SCAN_ITEMS;
#pragma unroll
    for (int i = 0; i < SCAN_ITEMS; i++) {
        int j = base + i;
        if (j < N) off[j] += add;
    }
}

// ---- scatter edge src ids into CSR slots (atomic-free via rank, u16) -------
__global__ __launch_bounds__(256) void scatter_kernel(
    const int* __restrict__ src, const int* __restrict__ dst,
    const int* __restrict__ off, const unsigned short* __restrict__ rank,
    unsigned short* __restrict__ esrc, int E, int N)
{
    int i = blockIdx.x * 256 + threadIdx.x;
    if (i >= E + N) return;
    int d, s;
    if (i < E) { d = dst[i]; s = src[i]; }
    else       { d = i - E; s = d; }
    esrc[off[d] + (int)rank[i]] = (unsigned short)s;
}

// ---- fused attn + final ----------------------------------------------------
// Block owns 64 nodes. Each wave: attn for its 16 nodes (round-4 gather),
// att rows -> LDS bf16. Barrier. Then 16-node MFMA tile vs Wc[128][256]
// (A k<128 from ndb, A k>=128 from att_lds), bias + row-L2-norm + relu.
__global__ __launch_bounds__(256) void attn_final_kernel(
    const unsigned short* __restrict__ ndb, const float* __restrict__ q,
    const float* __restrict__ kf, const int* __restrict__ off,
    const unsigned short* __restrict__ esrc,
    const unsigned short* __restrict__ Wc, const float* __restrict__ b2,
    float* __restrict__ out, int N)
{
    __shared__ unsigned short att_lds[64][ALD];

    const float INVDK = 0.28867513459481287f;  // 1/sqrt(12)
    int t = threadIdx.x;
    int wv = t >> 6;
    int lane = t & 63;
    int col = lane & 15;
    int quad = lane >> 4;
    int nbase = blockIdx.x * 64;

    // ---- attn: 16 nodes per wave, sequential ----
    for (int it = 0; it < 16; it++) {
        int wid = nbase + wv * 16 + it;
        if (wid >= N) break;

        int start = off[wid];
        int deg = off[wid + 1] - start;

        const float4* kp = (const float4*)(kf + (size_t)wid * QK_PAD);
        float4 c0 = kp[0], c1 = kp[1], c2 = kp[2];

        float2 acc = make_float2(0.f, 0.f);
        float inv;

        if (deg <= 64) {
            float sc = -INFINITY;
            int si = 0;
            if (lane < deg) {
                si = (int)esrc[start + lane];
                sc = dot12(q + (size_t)si * QK_PAD, c0, c1, c2) * INVDK;
            }
            float m = sc;
#pragma unroll
            for (int o = 32; o > 0; o >>= 1) m = fmaxf(m, __shfl_xor(m, o));
            float w = (lane < deg) ? __expf(sc - m) : 0.f;
            float lsum = w;
#pragma unroll
            for (int o = 32; o > 0; o >>= 1) lsum += __shfl_xor(lsum, o);
            inv = 1.f / lsum;

            int i = 0;
            for (; i + 4 <= deg; i += 4) {
                float w0 = __shfl(w, i);     int r0 = __shfl(si, i);
                float w1 = __shfl(w, i + 1); int r1 = __shfl(si, i + 1);
                float w2 = __shfl(w, i + 2); int r2 = __shfl(si, i + 2);
                float w3 = __shfl(w, i + 3); int r3 = __shfl(si, i + 3);
                unsigned v0 = *(const unsigned*)(ndb + (size_t)r0 * IN_F + lane * 2);
                unsigned v1 = *(const unsigned*)(ndb + (size_t)r1 * IN_F + lane * 2);
                unsigned v2 = *(const unsigned*)(ndb + (size_t)r2 * IN_F + lane * 2);
                unsigned v3 = *(const unsigned*)(ndb + (size_t)r3 * IN_F + lane * 2);
                float2 f0 = bf2x2(v0), f1 = bf2x2(v1), f2 = bf2x2(v2), f3 = bf2x2(v3);
                acc.x += w0 * f0.x + w1 * f1.x + w2 * f2.x + w3 * f3.x;
                acc.y += w0 * f0.y + w1 * f1.y + w2 * f2.y + w3 * f3.y;
            }
            for (; i < deg; i++) {
                float wi = __shfl(w, i);
                int r = __shfl(si, i);
                float2 f = bf2x2(*(const unsigned*)(ndb + (size_t)r * IN_F + lane * 2));
                acc.x += wi * f.x;
                acc.y += wi * f.y;
            }
        } else {
            // generic (deg > 64): recompute scores per pass
            float m = -INFINITY;
            for (int i = lane; i < deg; i += 64) {
                int s2 = (int)esrc[start + i];
                m = fmaxf(m, dot12(q + (size_t)s2 * QK_PAD, c0, c1, c2) * INVDK);
            }
#pragma unroll
            for (int o = 32; o > 0; o >>= 1) m = fmaxf(m, __shfl_xor(m, o));
            float lsum = 0.f;
            for (int i = lane; i < deg; i += 64) {
                int s2 = (int)esrc[start + i];
                lsum += __expf(dot12(q + (size_t)s2 * QK_PAD, c0, c1, c2) * INVDK - m);
            }
#pragma unroll
            for (int o = 32; o > 0; o >>= 1) lsum += __shfl_xor(lsum, o);
            inv = 1.f / lsum;
            for (int base2 = 0; base2 < deg; base2 += 64) {
                int cnt2 = deg - base2; if (cnt2 > 64) cnt2 = 64;
                float w = 0.f; int si = 0;
                if (lane < cnt2) {
                    si = (int)esrc[start + base2 + lane];
                    w = __expf(dot12(q + (size_t)si * QK_PAD, c0, c1, c2) * INVDK - m);
                }
                for (int i = 0; i < cnt2; i++) {
                    float wi = __shfl(w, i);
                    int r = __shfl(si, i);
                    float2 f = bf2x2(*(const unsigned*)(ndb + (size_t)r * IN_F + lane * 2));
                    acc.x += wi * f.x;
                    acc.y += wi * f.y;
                }
            }
        }
        acc.x *= inv; acc.y *= inv;
        // store att row (features 2*lane, 2*lane+1) as packed bf16 -> LDS
        unsigned pak = (unsigned)f2bf(acc.x) | ((unsigned)f2bf(acc.y) << 16);
        *(unsigned*)&att_lds[wv * 16 + it][lane * 2] = pak;
    }
    __syncthreads();

    // ---- final: 16-node MFMA tile per wave ----
    int arow = nbase + wv * 16 + col;
    int rowc = (arow < N) ? arow : (N - 1);
    const unsigned short* a0p = ndb + (size_t)rowc * IN_F + quad * 8;
    const unsigned short* alp = &att_lds[wv * 16 + col][quad * 8];

    f32x4 acc[8];
#pragma unroll
    for (int i = 0; i < 8; i++) acc[i] = (f32x4)0.f;

#pragma unroll
    for (int ks = 0; ks < 8; ks++) {
        int k0 = ks * 32;
        short8 a;
        if (ks < 4) a = *(const short8*)(a0p + k0);
        else        a = *(const short8*)(alp + (k0 - 128));
#pragma unroll
        for (int ft = 0; ft < 8; ft++) {
            int n = ft * 16 + col;
            short8 bb = *(const short8*)(Wc + (size_t)n * 256 + k0 + quad * 8);
            acc[ft] = __builtin_amdgcn_mfma_f32_16x16x32_bf16(a, bb, acc[ft], 0, 0, 0);
        }
    }

    float bias[8];
#pragma unroll
    for (int ft = 0; ft < 8; ft++) bias[ft] = b2[ft * 16 + col];

#pragma unroll
    for (int r = 0; r < 4; r++) {
        int node = nbase + wv * 16 + quad * 4 + r;
        float v[8];
        float ps = 0.f;
#pragma unroll
        for (int ft = 0; ft < 8; ft++) {
            v[ft] = acc[ft][r] + bias[ft];
            ps += v[ft] * v[ft];
        }
        ps += __shfl_xor(ps, 1);
        ps += __shfl_xor(ps, 2);
        ps += __shfl_xor(ps, 4);
        ps += __shfl_xor(ps, 8);
        float rn = rsqrtf(ps);
        if (node < N) {
            float* op = out + (size_t)node * 128 + col;
#pragma unroll
            for (int ft = 0; ft < 8; ft++)
                op[ft * 16] = fmaxf(v[ft] * rn, 0.f);
        }
    }
}

// ---------------------------------------------------------------------------
static inline char* align_up(char* p, size_t a) {
    return (char*)(((uintptr_t)p + (a - 1)) & ~(uintptr_t)(a - 1));
}

extern "C" void kernel_launch(void* const* d_in, const int* in_sizes, int n_in,
                              void* d_out, int out_size, void* d_ws, size_t ws_size,
                              hipStream_t stream) {
    const float* node_data = (const float*)d_in[0];
    const int*   src       = (const int*)d_in[1];
    const int*   dst       = (const int*)d_in[2];
    const float* Wq        = (const float*)d_in[3];
    const float* bq        = (const float*)d_in[4];
    const float* Wk        = (const float*)d_in[5];
    const float* bk        = (const float*)d_in[6];
    const float* W1        = (const float*)d_in[7];
    const float* W2        = (const float*)d_in[8];
    const float* b2        = (const float*)d_in[9];
    float* out = (float*)d_out;

    int N = in_sizes[0] / IN_F;
    int E = in_sizes[1];
    int ET = E + N;
    int NB = (N + SCAN_CHUNK - 1) / SCAN_CHUNK;   // 25 for N=50000
    int NBQK = (N + 63) / 64;                      // 782 (4 waves x 16 nodes)
    int NBCNT = 512;                               // grid-stride histogram
    int NBCVT = 128;                               // 32768 / 256
    int NT = (N + 63) / 64;                        // 782 fused-tile blocks

    char* w = (char*)d_ws;
    float* q  = (float*)w;  w += (size_t)N * QK_PAD * sizeof(float);
    float* kf = (float*)w;  w += (size_t)N * QK_PAD * sizeof(float);
    w = align_up(w, 256);
    unsigned short* ndb = (unsigned short*)w;  w += (size_t)N * IN_F * sizeof(unsigned short);
    w = align_up(w, 256);
    unsigned short* Wc = (unsigned short*)w;  w += 128 * 256 * sizeof(unsigned short);
    int* off  = (int*)w;  w += (size_t)(N + 1) * sizeof(int);
    int* bsum = (int*)w;  w += 256 * sizeof(int);
    unsigned short* rank = (unsigned short*)w;  w += (size_t)ET * sizeof(unsigned short);
    w = align_up(w, 256);
    unsigned short* esrc = (unsigned short*)w;  w += (size_t)ET * sizeof(unsigned short);

    hipMemsetAsync(off, 0, (size_t)(N + 1) * sizeof(int), stream);

    prep_kernel<<<NBQK + NBCNT + NBCVT, 256, 0, stream>>>(
        node_data, Wq, bq, Wk, bk, dst, W1, W2,
        q, kf, ndb, off, rank, Wc, N, E, NBQK, NBCNT);
    scan_local_kernel<<<NB, 256, 0, stream>>>(off, bsum, N);
    scan_add_kernel<<<NB, 256, 0, stream>>>(off, bsum, N, NB);
    scatter_kernel<<<(ET + 255) / 256, 256, 0, stream>>>(src, dst, off, rank, esrc, E, N);
    attn_final_kernel<<<NT, 256, 0, stream>>>(ndb, q, kf, off, esrc, Wc, b2, out, N);
}